// Round 1
// baseline (1074.342 us; speedup 1.0000x reference)
//
#include <hip/hip_runtime.h>
#include <hip/hip_bf16.h>
#include <stdint.h>

typedef unsigned short u16;

__device__ __forceinline__ float bf2f(u16 u) {
    return __uint_as_float(((uint32_t)u) << 16);
}
__device__ __forceinline__ u16 f2bf(float f) {
    uint32_t u = __float_as_uint(f);
    uint32_t r = u + 0x7fffu + ((u >> 16) & 1u);
    return (u16)(r >> 16);
}

__device__ __forceinline__ float ldf(const float* p) { return *p; }
__device__ __forceinline__ float ldf(const u16* p) { return bf2f(*p); }

// ---------------- init: deg=1 (self loop), cnt=0, fill=0 ----------------
__global__ void k_init(float* deg, int* cnt, int* fill, int n) {
    int i = blockIdx.x * 256 + threadIdx.x;
    if (i < n) { deg[i] = 1.0f; cnt[i] = 0; fill[i] = 0; }
}

// ---------------- weighted in-degree + in-edge count ----------------
__global__ void k_degcnt(const int* __restrict__ dst, const float* __restrict__ ew,
                         float* deg, int* cnt, int E) {
    int e = blockIdx.x * 256 + threadIdx.x;
    if (e < E) {
        int d = dst[e];
        atomicAdd(&deg[d], ew[e]);
        atomicAdd(&cnt[d], 1);
    }
}

// ---------------- dinv = rsqrt(deg) ----------------
__global__ void k_dinv(const float* __restrict__ deg, float* dinv, int n) {
    int i = blockIdx.x * 256 + threadIdx.x;
    if (i < n) {
        float d = deg[i];
        dinv[i] = d > 0.0f ? rsqrtf(d) : 0.0f;
    }
}

// ---------------- prefix scan (3 kernels) ----------------
__global__ void k_scan_block(const int* __restrict__ cnt, int* rowptr, int* bsum, int n) {
    __shared__ int s[256];
    int t = threadIdx.x;
    int i = blockIdx.x * 256 + t;
    int v = (i < n) ? cnt[i] : 0;
    s[t] = v;
    __syncthreads();
    for (int off = 1; off < 256; off <<= 1) {
        int x = (t >= off) ? s[t - off] : 0;
        __syncthreads();
        s[t] += x;
        __syncthreads();
    }
    if (i < n) rowptr[i] = s[t] - v;  // exclusive
    if (t == 255) bsum[blockIdx.x] = s[255];
}

__global__ void k_scan_sums(int* bsum, int nb) {
    __shared__ int s[512];
    int t = threadIdx.x;
    int v = (t < nb) ? bsum[t] : 0;
    s[t] = v;
    __syncthreads();
    for (int off = 1; off < 512; off <<= 1) {
        int x = (t >= off) ? s[t - off] : 0;
        __syncthreads();
        s[t] += x;
        __syncthreads();
    }
    if (t < nb) bsum[t] = s[t] - v;  // exclusive
}

__global__ void k_scan_add(int* rowptr, const int* __restrict__ bsum, int n) {
    int i = blockIdx.x * 256 + threadIdx.x;
    if (i < n) rowptr[i] += bsum[blockIdx.x];
}

// ---------------- scatter edges into CSR (packed {src, norm}) ----------------
__global__ void k_scatter(const int* __restrict__ src, const int* __restrict__ dst,
                          const float* __restrict__ ew, const float* __restrict__ dinv,
                          const int* __restrict__ rowptr, int* fill, int2* rec, int E) {
    int e = blockIdx.x * 256 + threadIdx.x;
    if (e < E) {
        int s = src[e], d = dst[e];
        float nrm = dinv[s] * ew[e] * dinv[d];
        int pos = rowptr[d] + atomicAdd(&fill[d], 1);
        rec[pos] = make_int2(s, __float_as_int(nrm));
    }
}

// ---------------- dense transform: out_bf16[n][128] = A[n][128] @ W[128][128] ----------------
// block 256 threads, 64 rows per block; LDS: A tile 32KB + W k-tile 16KB
template <typename TIn>
__global__ __launch_bounds__(256) void k_gemm(const TIn* __restrict__ A,
                                              const float* __restrict__ W,
                                              u16* __restrict__ outp, int n) {
    __shared__ float As[64][128];
    __shared__ float Ws[32][128];
    int t = threadIdx.x;
    int row0 = blockIdx.x * 64;

    for (int i = t; i < 64 * 128; i += 256) {
        int r = i >> 7, c = i & 127;
        int gr = row0 + r;
        As[r][c] = (gr < n) ? ldf(&A[(size_t)gr * 128 + c]) : 0.0f;
    }

    float acc[8][4];
#pragma unroll
    for (int i = 0; i < 8; i++)
#pragma unroll
        for (int j = 0; j < 4; j++) acc[i][j] = 0.0f;

    int c0 = (t & 31) * 4;
    int r0 = (t >> 5) * 8;

    for (int kt = 0; kt < 128; kt += 32) {
        __syncthreads();
        for (int i = t; i < 32 * 128; i += 256) {
            int kk = i >> 7, c = i & 127;
            Ws[kk][c] = W[(size_t)(kt + kk) * 128 + c];
        }
        __syncthreads();
#pragma unroll
        for (int kk = 0; kk < 32; kk += 4) {
            float w0[4], w1[4], w2[4], w3[4];
            *(float4*)w0 = *(const float4*)&Ws[kk + 0][c0];
            *(float4*)w1 = *(const float4*)&Ws[kk + 1][c0];
            *(float4*)w2 = *(const float4*)&Ws[kk + 2][c0];
            *(float4*)w3 = *(const float4*)&Ws[kk + 3][c0];
#pragma unroll
            for (int i = 0; i < 8; i++) {
                float a[4];
                *(float4*)a = *(const float4*)&As[r0 + i][kt + kk];
#pragma unroll
                for (int j = 0; j < 4; j++) {
                    acc[i][j] = fmaf(a[0], w0[j], acc[i][j]);
                    acc[i][j] = fmaf(a[1], w1[j], acc[i][j]);
                    acc[i][j] = fmaf(a[2], w2[j], acc[i][j]);
                    acc[i][j] = fmaf(a[3], w3[j], acc[i][j]);
                }
            }
        }
    }

#pragma unroll
    for (int i = 0; i < 8; i++) {
        int gr = row0 + r0 + i;
        if (gr < n) {
            ushort4 o;
            o.x = f2bf(acc[i][0]);
            o.y = f2bf(acc[i][1]);
            o.z = f2bf(acc[i][2]);
            o.w = f2bf(acc[i][3]);
            *reinterpret_cast<ushort4*>(&outp[(size_t)gr * 128 + c0]) = o;
        }
    }
}

// ---------------- aggregation: h[i] = relu(sum_e norm_e * t[src_e] + dinv[i]^2 * t[i] + b) ----------------
// one block (128 threads) per node; thread = channel
__global__ __launch_bounds__(128) void k_agg(const u16* __restrict__ t, const int2* __restrict__ rec,
                                             const int* __restrict__ rowptr, const int* __restrict__ cnt,
                                             const float* __restrict__ dinv, const float* __restrict__ bias,
                                             u16* __restrict__ hout, int n) {
    int i = blockIdx.x;
    int c = threadIdx.x;
    float di = dinv[i];
    float acc = di * di * bf2f(t[(size_t)i * 128 + c]);
    int start = rowptr[i];
    int m = cnt[i];
    int e = 0;
    for (; e + 4 <= m; e += 4) {
        int2 r0 = rec[start + e + 0];
        int2 r1 = rec[start + e + 1];
        int2 r2 = rec[start + e + 2];
        int2 r3 = rec[start + e + 3];
        float g0 = bf2f(t[(size_t)r0.x * 128 + c]);
        float g1 = bf2f(t[(size_t)r1.x * 128 + c]);
        float g2 = bf2f(t[(size_t)r2.x * 128 + c]);
        float g3 = bf2f(t[(size_t)r3.x * 128 + c]);
        acc = fmaf(__int_as_float(r0.y), g0, acc);
        acc = fmaf(__int_as_float(r1.y), g1, acc);
        acc = fmaf(__int_as_float(r2.y), g2, acc);
        acc = fmaf(__int_as_float(r3.y), g3, acc);
    }
    for (; e < m; e++) {
        int2 r = rec[start + e];
        acc = fmaf(__int_as_float(r.y), bf2f(t[(size_t)r.x * 128 + c]), acc);
    }
    acc += bias[c];
    acc = fmaxf(acc, 0.0f);
    hout[(size_t)i * 128 + c] = f2bf(acc);
}

// ---------------- final FC: value[i] = h2[i] . Wfc[0:128] + action[i]*Wfc[128] + bfc ----------------
__global__ __launch_bounds__(256) void k_fc(const u16* __restrict__ h, const float* __restrict__ action,
                                            const float* __restrict__ Wfc, const float* __restrict__ bfc,
                                            float* __restrict__ out, int n) {
    int gid = blockIdx.x * 256 + threadIdx.x;
    int wid = gid >> 6;  // one wave per node
    int lane = threadIdx.x & 63;
    if (wid >= n) return;
    float2 w = *reinterpret_cast<const float2*>(&Wfc[2 * lane]);
    uint32_t u = *reinterpret_cast<const uint32_t*>(&h[(size_t)wid * 128 + 2 * lane]);
    float v = bf2f((u16)(u & 0xffff)) * w.x + bf2f((u16)(u >> 16)) * w.y;
#pragma unroll
    for (int off = 32; off >= 1; off >>= 1) v += __shfl_down(v, off, 64);
    if (lane == 0) out[wid] = v + action[wid] * Wfc[128] + bfc[0];
}

extern "C" void kernel_launch(void* const* d_in, const int* in_sizes, int n_in,
                              void* d_out, int out_size, void* d_ws, size_t ws_size,
                              hipStream_t stream) {
    const float* x = (const float*)d_in[0];
    const int* ei = (const int*)d_in[1];
    const float* ew = (const float*)d_in[2];
    const float* action = (const float*)d_in[3];
    const float* W1 = (const float*)d_in[4];
    const float* b1 = (const float*)d_in[5];
    const float* W2 = (const float*)d_in[6];
    const float* b2 = (const float*)d_in[7];
    const float* Wfc = (const float*)d_in[8];
    const float* bfc = (const float*)d_in[9];
    float* out = (float*)d_out;

    int n = in_sizes[0] / 128;
    int E = in_sizes[2];
    const int* src = ei;
    const int* dst = ei + E;

    char* p = (char*)d_ws;
    auto carve = [&](size_t bytes) -> char* {
        char* q = p;
        p += (bytes + 255) & ~(size_t)255;
        return q;
    };
    float* deg = (float*)carve((size_t)n * 4);
    float* dinv = (float*)carve((size_t)n * 4);
    int* cnt = (int*)carve((size_t)n * 4);
    int* fill = (int*)carve((size_t)n * 4);
    int* rowptr = (int*)carve((size_t)n * 4);
    int* bsum = (int*)carve(1024 * 4);
    int2* rec = (int2*)carve((size_t)E * 8);
    u16* tbuf = (u16*)carve((size_t)n * 128 * 2);
    u16* hbuf = (u16*)carve((size_t)n * 128 * 2);

    int nb = (n + 255) / 256;

    k_init<<<nb, 256, 0, stream>>>(deg, cnt, fill, n);
    k_degcnt<<<(E + 255) / 256, 256, 0, stream>>>(dst, ew, deg, cnt, E);
    k_dinv<<<nb, 256, 0, stream>>>(deg, dinv, n);
    k_scan_block<<<nb, 256, 0, stream>>>(cnt, rowptr, bsum, n);
    k_scan_sums<<<1, 512, 0, stream>>>(bsum, nb);
    k_scan_add<<<nb, 256, 0, stream>>>(rowptr, bsum, n);
    k_scatter<<<(E + 255) / 256, 256, 0, stream>>>(src, dst, ew, dinv, rowptr, fill, rec, E);

    k_gemm<float><<<(n + 63) / 64, 256, 0, stream>>>(x, W1, tbuf, n);
    k_agg<<<n, 128, 0, stream>>>(tbuf, rec, rowptr, cnt, dinv, b1, hbuf, n);
    k_gemm<u16><<<(n + 63) / 64, 256, 0, stream>>>(hbuf, W2, tbuf, n);
    k_agg<<<n, 128, 0, stream>>>(tbuf, rec, rowptr, cnt, dinv, b2, hbuf, n);
    k_fc<<<((size_t)n * 64 + 255) / 256, 256, 0, stream>>>(hbuf, action, Wfc, bfc, out, n);
}

// Round 2
// 864.814 us; speedup vs baseline: 1.2423x; 1.2423x over previous
//
#include <hip/hip_runtime.h>
#include <hip/hip_bf16.h>
#include <stdint.h>

typedef unsigned short u16;
typedef unsigned long long u64;

__device__ __forceinline__ float bf2f(u16 u) {
    return __uint_as_float(((uint32_t)u) << 16);
}
__device__ __forceinline__ u16 f2bf(float f) {
    uint32_t u = __float_as_uint(f);
    uint32_t r = u + 0x7fffu + ((u >> 16) & 1u);
    return (u16)(r >> 16);
}

__device__ __forceinline__ float ldf(const float* p) { return *p; }
__device__ __forceinline__ float ldf(const u16* p) { return bf2f(*p); }

#define DEG_SCALE 4294967296.0f           // 2^32
#define DEG_INV 2.3283064365386963e-10f   // 2^-32

// ---------------- init: packed = {cnt=0 : 16 | degsum=1.0 : 48}  (self-loop) ----------------
__global__ void k_init(u64* packed, int n) {
    int i = blockIdx.x * 256 + threadIdx.x;
    if (i < n) packed[i] = (1ull << 32);
}

// ---------------- fused weighted in-degree + count: ONE 64-bit atomic per edge ----------------
__global__ void k_degcnt(const int* __restrict__ dst, const float* __restrict__ ew,
                         u64* packed, int E) {
    int e = blockIdx.x * 256 + threadIdx.x;
    if (e < E) {
        u64 add = (1ull << 48) | (u64)(ew[e] * DEG_SCALE);
        atomicAdd(&packed[dst[e]], add);
    }
}

// ---------------- dinv = rsqrt(deg)  (deg >= 1 always: self-loop) ----------------
__global__ void k_dinv(const u64* __restrict__ packed, float* dinv, int n) {
    int i = blockIdx.x * 256 + threadIdx.x;
    if (i < n) {
        float deg = (float)(packed[i] & 0xFFFFFFFFFFFFull) * DEG_INV;
        dinv[i] = rsqrtf(deg);
    }
}

// ---------------- prefix scan over cnt (3 kernels) ----------------
__global__ void k_scan_block(const u64* __restrict__ packed, int* rowptr, int* bsum, int n) {
    __shared__ int s[256];
    int t = threadIdx.x;
    int i = blockIdx.x * 256 + t;
    int v = (i < n) ? (int)(packed[i] >> 48) : 0;
    s[t] = v;
    __syncthreads();
    for (int off = 1; off < 256; off <<= 1) {
        int x = (t >= off) ? s[t - off] : 0;
        __syncthreads();
        s[t] += x;
        __syncthreads();
    }
    if (i < n) rowptr[i] = s[t] - v;  // exclusive
    if (t == 255) bsum[blockIdx.x] = s[255];
}

__global__ void k_scan_sums(int* bsum, int nb) {
    __shared__ int s[512];
    int t = threadIdx.x;
    int v = (t < nb) ? bsum[t] : 0;
    s[t] = v;
    __syncthreads();
    for (int off = 1; off < 512; off <<= 1) {
        int x = (t >= off) ? s[t - off] : 0;
        __syncthreads();
        s[t] += x;
        __syncthreads();
    }
    if (t < nb) bsum[t] = s[t] - v;  // exclusive
}

__global__ void k_scan_add(int* rowptr, const int* __restrict__ bsum, int* wptr, int n) {
    int i = blockIdx.x * 256 + threadIdx.x;
    if (i < n) {
        int v = rowptr[i] + bsum[blockIdx.x];
        rowptr[i] = v;
        wptr[i] = v;
    }
}

// ---------------- scatter edges into CSR (packed {src, norm}); wptr doubles as fill ----------------
__global__ void k_scatter(const int* __restrict__ src, const int* __restrict__ dst,
                          const float* __restrict__ ew, const float* __restrict__ dinv,
                          int* wptr, int2* rec, int E) {
    int e = blockIdx.x * 256 + threadIdx.x;
    if (e < E) {
        int s = src[e], d = dst[e];
        float nrm = dinv[s] * ew[e] * dinv[d];
        int pos = atomicAdd(&wptr[d], 1);
        rec[pos] = make_int2(s, __float_as_int(nrm));
    }
}

// ---------------- dense transform: out_bf16[n][128] = A[n][128] @ W[128][128] ----------------
template <typename TIn>
__global__ __launch_bounds__(256) void k_gemm(const TIn* __restrict__ A,
                                              const float* __restrict__ W,
                                              u16* __restrict__ outp, int n) {
    __shared__ float As[64][128];
    __shared__ float Ws[32][128];
    int t = threadIdx.x;
    int row0 = blockIdx.x * 64;

    for (int i = t; i < 64 * 128; i += 256) {
        int r = i >> 7, c = i & 127;
        int gr = row0 + r;
        As[r][c] = (gr < n) ? ldf(&A[(size_t)gr * 128 + c]) : 0.0f;
    }

    float acc[8][4];
#pragma unroll
    for (int i = 0; i < 8; i++)
#pragma unroll
        for (int j = 0; j < 4; j++) acc[i][j] = 0.0f;

    int c0 = (t & 31) * 4;
    int r0 = (t >> 5) * 8;

    for (int kt = 0; kt < 128; kt += 32) {
        __syncthreads();
        for (int i = t; i < 32 * 128; i += 256) {
            int kk = i >> 7, c = i & 127;
            Ws[kk][c] = W[(size_t)(kt + kk) * 128 + c];
        }
        __syncthreads();
#pragma unroll
        for (int kk = 0; kk < 32; kk += 4) {
            float w0[4], w1[4], w2[4], w3[4];
            *(float4*)w0 = *(const float4*)&Ws[kk + 0][c0];
            *(float4*)w1 = *(const float4*)&Ws[kk + 1][c0];
            *(float4*)w2 = *(const float4*)&Ws[kk + 2][c0];
            *(float4*)w3 = *(const float4*)&Ws[kk + 3][c0];
#pragma unroll
            for (int i = 0; i < 8; i++) {
                float a[4];
                *(float4*)a = *(const float4*)&As[r0 + i][kt + kk];
#pragma unroll
                for (int j = 0; j < 4; j++) {
                    acc[i][j] = fmaf(a[0], w0[j], acc[i][j]);
                    acc[i][j] = fmaf(a[1], w1[j], acc[i][j]);
                    acc[i][j] = fmaf(a[2], w2[j], acc[i][j]);
                    acc[i][j] = fmaf(a[3], w3[j], acc[i][j]);
                }
            }
        }
    }

#pragma unroll
    for (int i = 0; i < 8; i++) {
        int gr = row0 + r0 + i;
        if (gr < n) {
            ushort4 o;
            o.x = f2bf(acc[i][0]);
            o.y = f2bf(acc[i][1]);
            o.z = f2bf(acc[i][2]);
            o.w = f2bf(acc[i][3]);
            *reinterpret_cast<ushort4*>(&outp[(size_t)gr * 128 + c0]) = o;
        }
    }
}

// ---------------- aggregation: wave per node, lane = 2 channels ----------------
__global__ __launch_bounds__(256) void k_agg(const u16* __restrict__ t, const int2* __restrict__ rec,
                                             const int* __restrict__ rowptr, const u64* __restrict__ packed,
                                             const float* __restrict__ dinv, const float* __restrict__ bias,
                                             u16* __restrict__ hout, int n) {
    int node = blockIdx.x * 4 + (threadIdx.x >> 6);
    if (node >= n) return;
    int lane = threadIdx.x & 63;
    float di = dinv[node];
    float sdi = di * di;
    uint32_t u0 = *reinterpret_cast<const uint32_t*>(&t[(size_t)node * 128 + 2 * lane]);
    float acc0 = sdi * bf2f((u16)(u0 & 0xffff));
    float acc1 = sdi * bf2f((u16)(u0 >> 16));
    int start = rowptr[node];
    int m = (int)(packed[node] >> 48);
    int e = 0;
    for (; e + 4 <= m; e += 4) {
        int2 r0 = rec[start + e + 0];
        int2 r1 = rec[start + e + 1];
        int2 r2 = rec[start + e + 2];
        int2 r3 = rec[start + e + 3];
        uint32_t g0 = *reinterpret_cast<const uint32_t*>(&t[(size_t)r0.x * 128 + 2 * lane]);
        uint32_t g1 = *reinterpret_cast<const uint32_t*>(&t[(size_t)r1.x * 128 + 2 * lane]);
        uint32_t g2 = *reinterpret_cast<const uint32_t*>(&t[(size_t)r2.x * 128 + 2 * lane]);
        uint32_t g3 = *reinterpret_cast<const uint32_t*>(&t[(size_t)r3.x * 128 + 2 * lane]);
        float n0 = __int_as_float(r0.y), n1 = __int_as_float(r1.y);
        float n2 = __int_as_float(r2.y), n3 = __int_as_float(r3.y);
        acc0 = fmaf(n0, bf2f((u16)(g0 & 0xffff)), acc0);
        acc1 = fmaf(n0, bf2f((u16)(g0 >> 16)), acc1);
        acc0 = fmaf(n1, bf2f((u16)(g1 & 0xffff)), acc0);
        acc1 = fmaf(n1, bf2f((u16)(g1 >> 16)), acc1);
        acc0 = fmaf(n2, bf2f((u16)(g2 & 0xffff)), acc0);
        acc1 = fmaf(n2, bf2f((u16)(g2 >> 16)), acc1);
        acc0 = fmaf(n3, bf2f((u16)(g3 & 0xffff)), acc0);
        acc1 = fmaf(n3, bf2f((u16)(g3 >> 16)), acc1);
    }
    for (; e < m; e++) {
        int2 r = rec[start + e];
        uint32_t g = *reinterpret_cast<const uint32_t*>(&t[(size_t)r.x * 128 + 2 * lane]);
        float nn = __int_as_float(r.y);
        acc0 = fmaf(nn, bf2f((u16)(g & 0xffff)), acc0);
        acc1 = fmaf(nn, bf2f((u16)(g >> 16)), acc1);
    }
    float2 b = *reinterpret_cast<const float2*>(&bias[2 * lane]);
    acc0 = fmaxf(acc0 + b.x, 0.0f);
    acc1 = fmaxf(acc1 + b.y, 0.0f);
    uint32_t o = (uint32_t)f2bf(acc0) | ((uint32_t)f2bf(acc1) << 16);
    *reinterpret_cast<uint32_t*>(&hout[(size_t)node * 128 + 2 * lane]) = o;
}

// ---------------- final FC: value[i] = h2[i] . Wfc[0:128] + action[i]*Wfc[128] + bfc ----------------
__global__ __launch_bounds__(256) void k_fc(const u16* __restrict__ h, const float* __restrict__ action,
                                            const float* __restrict__ Wfc, const float* __restrict__ bfc,
                                            float* __restrict__ out, int n) {
    int gid = blockIdx.x * 256 + threadIdx.x;
    int wid = gid >> 6;  // one wave per node
    int lane = threadIdx.x & 63;
    if (wid >= n) return;
    float2 w = *reinterpret_cast<const float2*>(&Wfc[2 * lane]);
    uint32_t u = *reinterpret_cast<const uint32_t*>(&h[(size_t)wid * 128 + 2 * lane]);
    float v = bf2f((u16)(u & 0xffff)) * w.x + bf2f((u16)(u >> 16)) * w.y;
#pragma unroll
    for (int off = 32; off >= 1; off >>= 1) v += __shfl_down(v, off, 64);
    if (lane == 0) out[wid] = v + action[wid] * Wfc[128] + bfc[0];
}

extern "C" void kernel_launch(void* const* d_in, const int* in_sizes, int n_in,
                              void* d_out, int out_size, void* d_ws, size_t ws_size,
                              hipStream_t stream) {
    const float* x = (const float*)d_in[0];
    const int* ei = (const int*)d_in[1];
    const float* ew = (const float*)d_in[2];
    const float* action = (const float*)d_in[3];
    const float* W1 = (const float*)d_in[4];
    const float* b1 = (const float*)d_in[5];
    const float* W2 = (const float*)d_in[6];
    const float* b2 = (const float*)d_in[7];
    const float* Wfc = (const float*)d_in[8];
    const float* bfc = (const float*)d_in[9];
    float* out = (float*)d_out;

    int n = in_sizes[0] / 128;
    int E = in_sizes[2];
    const int* src = ei;
    const int* dst = ei + E;

    char* p = (char*)d_ws;
    auto carve = [&](size_t bytes) -> char* {
        char* q = p;
        p += (bytes + 255) & ~(size_t)255;
        return q;
    };
    u64* packed = (u64*)carve((size_t)n * 8);
    float* dinv = (float*)carve((size_t)n * 4);
    int* rowptr = (int*)carve((size_t)n * 4);
    int* wptr = (int*)carve((size_t)n * 4);
    int* bsum = (int*)carve(1024 * 4);
    int2* rec = (int2*)carve((size_t)E * 8);
    u16* tbuf = (u16*)carve((size_t)n * 128 * 2);
    u16* hbuf = (u16*)carve((size_t)n * 128 * 2);

    int nb = (n + 255) / 256;

    k_init<<<nb, 256, 0, stream>>>(packed, n);
    k_degcnt<<<(E + 255) / 256, 256, 0, stream>>>(dst, ew, packed, E);
    k_dinv<<<nb, 256, 0, stream>>>(packed, dinv, n);
    k_scan_block<<<nb, 256, 0, stream>>>(packed, rowptr, bsum, n);
    k_scan_sums<<<1, 512, 0, stream>>>(bsum, nb);
    k_scan_add<<<nb, 256, 0, stream>>>(rowptr, bsum, wptr, n);
    k_scatter<<<(E + 255) / 256, 256, 0, stream>>>(src, dst, ew, dinv, wptr, rec, E);

    k_gemm<float><<<(n + 63) / 64, 256, 0, stream>>>(x, W1, tbuf, n);
    k_agg<<<(n + 3) / 4, 256, 0, stream>>>(tbuf, rec, rowptr, packed, dinv, b1, hbuf, n);
    k_gemm<u16><<<(n + 63) / 64, 256, 0, stream>>>(hbuf, W2, tbuf, n);
    k_agg<<<(n + 3) / 4, 256, 0, stream>>>(tbuf, rec, rowptr, packed, dinv, b2, hbuf, n);
    k_fc<<<((size_t)n * 64 + 255) / 256, 256, 0, stream>>>(hbuf, action, Wfc, bfc, out, n);
}

// Round 5
// 712.280 us; speedup vs baseline: 1.5083x; 1.2141x over previous
//
#include <hip/hip_runtime.h>
#include <hip/hip_bf16.h>
#include <stdint.h>

typedef unsigned short u16;
typedef unsigned long long u64;

__device__ __forceinline__ float bf2f(u16 u) {
    return __uint_as_float(((uint32_t)u) << 16);
}
__device__ __forceinline__ u16 f2bf(float f) {
    uint32_t u = __float_as_uint(f);
    uint32_t r = u + 0x7fffu + ((u >> 16) & 1u);
    return (u16)(r >> 16);
}

__device__ __forceinline__ float ldf(const float* p) { return *p; }
__device__ __forceinline__ float ldf(const u16* p) { return bf2f(*p); }

#define DEG_SCALE 4294967296.0f           // 2^32
#define DEG_INV 2.3283064365386963e-10f   // 2^-32

// ---------------- init: packed = {cnt=0 : 16 | degsum=1.0 : 48}  (self-loop) ----------------
__global__ void k_init(u64* packed, int n) {
    int i = blockIdx.x * 256 + threadIdx.x;
    if (i < n) packed[i] = (1ull << 32);
}

// ---------------- 32-row GEMM tile as a device function (shared by both layers) ----------------
// out_bf16[32][128] = A[32][128] @ W[128][128]; 256 threads; 32KB LDS
template <typename TIn>
__device__ __forceinline__ void gemm_block(const TIn* __restrict__ A, const float* __restrict__ W,
                                           u16* __restrict__ outp, int n, int bid) {
    __shared__ float As[32][128];
    __shared__ float Ws[32][128];
    int t = threadIdx.x;
    int row0 = bid * 32;

    if constexpr (sizeof(TIn) == 2) {
        // bf16 input: stage via uint32 (2 ch per load)
        for (int i = t; i < 32 * 64; i += 256) {
            int r = i >> 6, c2 = i & 63;
            int gr = row0 + r;
            uint32_t u = (gr < n) ? *reinterpret_cast<const uint32_t*>(&A[(size_t)gr * 128 + 2 * c2]) : 0u;
            As[r][2 * c2] = bf2f((u16)(u & 0xffff));
            As[r][2 * c2 + 1] = bf2f((u16)(u >> 16));
        }
    } else {
        for (int i = t; i < 32 * 128; i += 256) {
            int r = i >> 7, c = i & 127;
            int gr = row0 + r;
            As[r][c] = (gr < n) ? ldf(&A[(size_t)gr * 128 + c]) : 0.0f;
        }
    }

    float acc[4][4];
#pragma unroll
    for (int i = 0; i < 4; i++)
#pragma unroll
        for (int j = 0; j < 4; j++) acc[i][j] = 0.0f;

    int c0 = (t & 31) * 4;
    int r0 = (t >> 5) * 4;

    for (int kt = 0; kt < 128; kt += 32) {
        __syncthreads();
        for (int i = t; i < 32 * 128; i += 256) {
            int kk = i >> 7, c = i & 127;
            Ws[kk][c] = W[(size_t)(kt + kk) * 128 + c];
        }
        __syncthreads();
#pragma unroll
        for (int kk = 0; kk < 32; kk += 4) {
            float w0[4], w1[4], w2[4], w3[4];
            *(float4*)w0 = *(const float4*)&Ws[kk + 0][c0];
            *(float4*)w1 = *(const float4*)&Ws[kk + 1][c0];
            *(float4*)w2 = *(const float4*)&Ws[kk + 2][c0];
            *(float4*)w3 = *(const float4*)&Ws[kk + 3][c0];
#pragma unroll
            for (int i = 0; i < 4; i++) {
                float a[4];
                *(float4*)a = *(const float4*)&As[r0 + i][kt + kk];
#pragma unroll
                for (int j = 0; j < 4; j++) {
                    acc[i][j] = fmaf(a[0], w0[j], acc[i][j]);
                    acc[i][j] = fmaf(a[1], w1[j], acc[i][j]);
                    acc[i][j] = fmaf(a[2], w2[j], acc[i][j]);
                    acc[i][j] = fmaf(a[3], w3[j], acc[i][j]);
                }
            }
        }
    }

#pragma unroll
    for (int i = 0; i < 4; i++) {
        int gr = row0 + r0 + i;
        if (gr < n) {
            ushort4 o;
            o.x = f2bf(acc[i][0]);
            o.y = f2bf(acc[i][1]);
            o.z = f2bf(acc[i][2]);
            o.w = f2bf(acc[i][3]);
            *reinterpret_cast<ushort4*>(&outp[(size_t)gr * 128 + c0]) = o;
        }
    }
}

// ---------------- fused: [gemm1 | degcnt] round-robin block roles ----------------
// role: bid%5==0 -> gemm block bid/5 (Gg total); else degcnt block 4*(bid/5)+(bid%5-1)
__global__ __launch_bounds__(256) void k_deg_gemm(const float* __restrict__ x, const float* __restrict__ W1,
                                                  u16* __restrict__ tbuf, int n, int Gg,
                                                  const int* __restrict__ dst, const float* __restrict__ ew,
                                                  u64* packed, int E) {
    int bid = blockIdx.x;
    int g = bid / 5;
    int r = bid - g * 5;
    if (r == 0 && g < Gg) {
        gemm_block<float>(x, W1, tbuf, n, g);
    } else if (r != 0) {
        int db = 4 * g + (r - 1);
        int e = db * 256 + threadIdx.x;
        if (e < E) {
            u64 add = (1ull << 48) | (u64)(ew[e] * DEG_SCALE);
            atomicAdd(&packed[dst[e]], add);
        }
    }
}

// ---------------- fused dinv + block-level exclusive scan of cnt ----------------
__global__ void k_dinv_scan(const u64* __restrict__ packed, float* dinv, int* rowptr, int* bsum, int n) {
    __shared__ int s[256];
    int t = threadIdx.x;
    int i = blockIdx.x * 256 + t;
    u64 pk = (i < n) ? packed[i] : 0;
    if (i < n) {
        float deg = (float)(pk & 0xFFFFFFFFFFFFull) * DEG_INV;
        dinv[i] = rsqrtf(deg);
    }
    int v = (int)(pk >> 48);
    s[t] = v;
    __syncthreads();
    for (int off = 1; off < 256; off <<= 1) {
        int x = (t >= off) ? s[t - off] : 0;
        __syncthreads();
        s[t] += x;
        __syncthreads();
    }
    if (i < n) rowptr[i] = s[t] - v;  // exclusive
    if (t == 255) bsum[blockIdx.x] = s[255];
}

__global__ void k_scan_sums(int* bsum, int nb) {
    __shared__ int s[512];
    int t = threadIdx.x;
    int v = (t < nb) ? bsum[t] : 0;
    s[t] = v;
    __syncthreads();
    for (int off = 1; off < 512; off <<= 1) {
        int x = (t >= off) ? s[t - off] : 0;
        __syncthreads();
        s[t] += x;
        __syncthreads();
    }
    if (t < nb) bsum[t] = s[t] - v;  // exclusive
}

__global__ void k_scan_add(int* rowptr, const int* __restrict__ bsum, int* wptr, int n) {
    int i = blockIdx.x * 256 + threadIdx.x;
    if (i < n) {
        int v = rowptr[i] + bsum[blockIdx.x];
        rowptr[i] = v;
        wptr[i] = v;
    }
}

// ---------------- scatter edges into CSR (packed {src, norm}); wptr doubles as fill ----------------
__global__ void k_scatter(const int* __restrict__ src, const int* __restrict__ dst,
                          const float* __restrict__ ew, const float* __restrict__ dinv,
                          int* wptr, int2* rec, int E) {
    int e = blockIdx.x * 256 + threadIdx.x;
    if (e < E) {
        int s = src[e], d = dst[e];
        float nrm = dinv[s] * ew[e] * dinv[d];
        int pos = atomicAdd(&wptr[d], 1);
        rec[pos] = make_int2(s, __float_as_int(nrm));
    }
}

// ---------------- standalone gemm (layer 2) ----------------
template <typename TIn>
__global__ __launch_bounds__(256) void k_gemm(const TIn* __restrict__ A, const float* __restrict__ W,
                                              u16* __restrict__ outp, int n) {
    gemm_block<TIn>(A, W, outp, n, blockIdx.x);
}

// ---------------- aggregation: wave per node, half-wave per edge, lane = 4 channels ----------------
// MODE 0: write relu(agg)+bias to hout (bf16).  MODE 1: fused final FC -> out.
template <int MODE>
__global__ __launch_bounds__(256) void k_agg(const u16* __restrict__ t, const int2* __restrict__ rec,
                                             const int* __restrict__ rowptr, const u64* __restrict__ packed,
                                             const float* __restrict__ dinv, const float* __restrict__ bias,
                                             u16* __restrict__ hout,
                                             const float* __restrict__ action, const float* __restrict__ Wfc,
                                             const float* __restrict__ bfc, float* __restrict__ out, int n) {
    int node = blockIdx.x * 4 + (threadIdx.x >> 6);
    if (node >= n) return;
    int lane = threadIdx.x & 63;
    int half = lane >> 5;
    int c4 = (lane & 31) * 4;
    int base = rowptr[node];
    int m = (int)(packed[node] >> 48);

    float4 acc = make_float4(0.f, 0.f, 0.f, 0.f);
    int e = 0;
    for (; e + 8 <= m; e += 8) {
        int2 r0 = rec[base + e + 0 + half];
        int2 r1 = rec[base + e + 2 + half];
        int2 r2 = rec[base + e + 4 + half];
        int2 r3 = rec[base + e + 6 + half];
        ushort4 g0 = *reinterpret_cast<const ushort4*>(&t[(size_t)r0.x * 128 + c4]);
        ushort4 g1 = *reinterpret_cast<const ushort4*>(&t[(size_t)r1.x * 128 + c4]);
        ushort4 g2 = *reinterpret_cast<const ushort4*>(&t[(size_t)r2.x * 128 + c4]);
        ushort4 g3 = *reinterpret_cast<const ushort4*>(&t[(size_t)r3.x * 128 + c4]);
        float n0 = __int_as_float(r0.y), n1 = __int_as_float(r1.y);
        float n2 = __int_as_float(r2.y), n3 = __int_as_float(r3.y);
        acc.x = fmaf(n0, bf2f(g0.x), acc.x); acc.y = fmaf(n0, bf2f(g0.y), acc.y);
        acc.z = fmaf(n0, bf2f(g0.z), acc.z); acc.w = fmaf(n0, bf2f(g0.w), acc.w);
        acc.x = fmaf(n1, bf2f(g1.x), acc.x); acc.y = fmaf(n1, bf2f(g1.y), acc.y);
        acc.z = fmaf(n1, bf2f(g1.z), acc.z); acc.w = fmaf(n1, bf2f(g1.w), acc.w);
        acc.x = fmaf(n2, bf2f(g2.x), acc.x); acc.y = fmaf(n2, bf2f(g2.y), acc.y);
        acc.z = fmaf(n2, bf2f(g2.z), acc.z); acc.w = fmaf(n2, bf2f(g2.w), acc.w);
        acc.x = fmaf(n3, bf2f(g3.x), acc.x); acc.y = fmaf(n3, bf2f(g3.y), acc.y);
        acc.z = fmaf(n3, bf2f(g3.z), acc.z); acc.w = fmaf(n3, bf2f(g3.w), acc.w);
    }
    for (; e + 2 <= m; e += 2) {
        int2 r = rec[base + e + half];
        ushort4 g = *reinterpret_cast<const ushort4*>(&t[(size_t)r.x * 128 + c4]);
        float nn = __int_as_float(r.y);
        acc.x = fmaf(nn, bf2f(g.x), acc.x); acc.y = fmaf(nn, bf2f(g.y), acc.y);
        acc.z = fmaf(nn, bf2f(g.z), acc.z); acc.w = fmaf(nn, bf2f(g.w), acc.w);
    }
    if (e < m && half == 0) {
        int2 r = rec[base + e];
        ushort4 g = *reinterpret_cast<const ushort4*>(&t[(size_t)r.x * 128 + c4]);
        float nn = __int_as_float(r.y);
        acc.x = fmaf(nn, bf2f(g.x), acc.x); acc.y = fmaf(nn, bf2f(g.y), acc.y);
        acc.z = fmaf(nn, bf2f(g.z), acc.z); acc.w = fmaf(nn, bf2f(g.w), acc.w);
    }
    // combine the two half-wave partial sums
    acc.x += __shfl_xor(acc.x, 32);
    acc.y += __shfl_xor(acc.y, 32);
    acc.z += __shfl_xor(acc.z, 32);
    acc.w += __shfl_xor(acc.w, 32);

    if (half == 0) {
        float di = dinv[node];
        float sdi = di * di;
        ushort4 sv = *reinterpret_cast<const ushort4*>(&t[(size_t)node * 128 + c4]);
        acc.x = fmaf(sdi, bf2f(sv.x), acc.x);
        acc.y = fmaf(sdi, bf2f(sv.y), acc.y);
        acc.z = fmaf(sdi, bf2f(sv.z), acc.z);
        acc.w = fmaf(sdi, bf2f(sv.w), acc.w);
        float4 b = *reinterpret_cast<const float4*>(&bias[c4]);
        acc.x = fmaxf(acc.x + b.x, 0.0f);
        acc.y = fmaxf(acc.y + b.y, 0.0f);
        acc.z = fmaxf(acc.z + b.z, 0.0f);
        acc.w = fmaxf(acc.w + b.w, 0.0f);
        if (MODE == 0) {
            ushort4 o;
            o.x = f2bf(acc.x); o.y = f2bf(acc.y); o.z = f2bf(acc.z); o.w = f2bf(acc.w);
            *reinterpret_cast<ushort4*>(&hout[(size_t)node * 128 + c4]) = o;
        } else {
            float4 w = *reinterpret_cast<const float4*>(&Wfc[c4]);
            float v = acc.x * w.x + acc.y * w.y + acc.z * w.z + acc.w * w.w;
#pragma unroll
            for (int off = 16; off >= 1; off >>= 1) v += __shfl_down(v, off, 32);
            if (lane == 0) out[node] = v + action[node] * Wfc[128] + bfc[0];
        }
    }
}

extern "C" void kernel_launch(void* const* d_in, const int* in_sizes, int n_in,
                              void* d_out, int out_size, void* d_ws, size_t ws_size,
                              hipStream_t stream) {
    const float* x = (const float*)d_in[0];
    const int* ei = (const int*)d_in[1];
    const float* ew = (const float*)d_in[2];
    const float* action = (const float*)d_in[3];
    const float* W1 = (const float*)d_in[4];
    const float* b1 = (const float*)d_in[5];
    const float* W2 = (const float*)d_in[6];
    const float* b2 = (const float*)d_in[7];
    const float* Wfc = (const float*)d_in[8];
    const float* bfc = (const float*)d_in[9];
    float* out = (float*)d_out;

    int n = in_sizes[0] / 128;
    int E = in_sizes[2];
    const int* src = ei;
    const int* dst = ei + E;

    char* p = (char*)d_ws;
    auto carve = [&](size_t bytes) -> char* {
        char* q = p;
        p += (bytes + 255) & ~(size_t)255;
        return q;
    };
    u64* packed = (u64*)carve((size_t)n * 8);
    float* dinv = (float*)carve((size_t)n * 4);
    int* rowptr = (int*)carve((size_t)n * 4);
    int* wptr = (int*)carve((size_t)n * 4);
    int* bsum = (int*)carve(1024 * 4);
    int2* rec = (int2*)carve(((size_t)E + 16) * 8);
    u16* tbuf = (u16*)carve((size_t)n * 128 * 2);
    u16* hbuf = (u16*)carve((size_t)n * 128 * 2);

    int nb = (n + 255) / 256;
    int Gg = (n + 31) / 32;              // gemm blocks (32-row tiles)
    int Gd = (E + 255) / 256;            // degcnt blocks
    // round-robin 1:4 interleave requires Gd == 4*Gg region coverage; launch enough groups
    int groups = (Gg > (Gd + 3) / 4) ? Gg : (Gd + 3) / 4;

    k_init<<<nb, 256, 0, stream>>>(packed, n);
    k_deg_gemm<<<groups * 5, 256, 0, stream>>>(x, W1, tbuf, n, Gg, dst, ew, packed, E);
    k_dinv_scan<<<nb, 256, 0, stream>>>(packed, dinv, rowptr, bsum, n);
    k_scan_sums<<<1, 512, 0, stream>>>(bsum, nb);
    k_scan_add<<<nb, 256, 0, stream>>>(rowptr, bsum, wptr, n);
    k_scatter<<<(E + 255) / 256, 256, 0, stream>>>(src, dst, ew, dinv, wptr, rec, E);

    k_agg<0><<<(n + 3) / 4, 256, 0, stream>>>(tbuf, rec, rowptr, packed, dinv, b1, hbuf,
                                              nullptr, nullptr, nullptr, nullptr, n);
    k_gemm<u16><<<(n + 31) / 32, 256, 0, stream>>>(hbuf, W2, tbuf, n);
    k_agg<1><<<(n + 3) / 4, 256, 0, stream>>>(tbuf, rec, rowptr, packed, dinv, b2, nullptr,
                                              action, Wfc, bfc, out, n);
}